// Round 3
// baseline (1430.534 us; speedup 1.0000x reference)
//
#include <hip/hip_runtime.h>
#include <hip/hip_bf16.h>
#include <math.h>

// RTM identities:
//  - softmax over size-1 axis == 1  =>  q,k,Wq,Wk dead; newV == v
//  - token j restarts from s0[:,j]; only cumV couples tokens
//  - prefix-sum linear => fold Wv into Wo: Wvo[a] = Wo[a] @ Wv[a] (once);
//       S1 = PS(LN1(T)) @ Wvo[a]^T + T
// R5: counted-vmcnt 3-buf @3 blocks/CU — neutral (TLP already hid the drain).
// R6: 256x256 deep pipeline @1 block/CU — REGRESSED (occupancy was the hiding
//     mechanism; 192-block grid left 25% of CUs idle).
// R7: occupancy-first. BN=64 tiles, 2-buf LDS (24 KiB) + <=85 VGPR
//     (__launch_bounds__(256,6)) -> 6 blocks/CU = 24 waves/CU; grids sized to
//     1536 blocks (fc1 32x48; fc2 split-K x4 32x12x4). Single-__syncthreads
//     loop (R0-proven). Bijective XCD-chunked tile remap for L2 locality on
//     the now-heavier A-panel refetch.

using bf16   = __bf16;
using bf16x8 = __attribute__((ext_vector_type(8))) __bf16;
using f32x4  = __attribute__((ext_vector_type(4))) float;

#define DEV __device__ __forceinline__

DEV void gload16(const bf16* g, bf16* l) {
  __builtin_amdgcn_global_load_lds(
      (const __attribute__((address_space(1))) unsigned int*)g,
      (__attribute__((address_space(3))) unsigned int*)l, 16, 0, 0);
}

// GELU with A&S 7.1.26 erf (abs err 1.5e-7; << bf16 rounding).
DEV float gelu_f(float x) {
  const float y  = x * 0.70710678118654752f;
  const float ay = fabsf(y);
  const float t  = __builtin_amdgcn_rcpf(__builtin_fmaf(0.3275911f, ay, 1.0f));
  float p = __builtin_fmaf(1.061405429f, t, -1.453152027f);
  p = __builtin_fmaf(p, t, 1.421413741f);
  p = __builtin_fmaf(p, t, -0.284496736f);
  p = __builtin_fmaf(p, t, 0.254829592f);
  p = p * t;
  const float e = __expf(-ay * ay);
  float er = __builtin_fmaf(-p, e, 1.0f);
  er = __builtin_copysignf(er, y);
  return 0.5f * x * (1.0f + er);
}

enum { EPI_PART = 0, EPI_GELU = 1, EPI_B16 = 2 };

// C[128 x BN tile] = A[M,K(+z*aZ)] @ B[N,K(+z*bZ)]^T over k in [z*kZ, z*kZ+klen).
// LDS layout: row-major [row][4 slots of 8 bf16], slot s of row r holds global
// chunk kq = (s - (r>>1)) & 3  (xor/rotate swizzle -> 2-way bank floor).
// 2-deep LDS buffers, one __syncthreads per K-iter (own-wave vmcnt/lgkm drain
// at the barrier is the correctness fence; 24 waves/CU hides it).
template <int BN, int EPI>
__global__ __launch_bounds__(256, 6) void gemm_k(
    const bf16* __restrict__ A, const bf16* __restrict__ B,
    float* __restrict__ outF, bf16* __restrict__ outB,
    const float* __restrict__ aux, int K, int N,
    int kZ, int klen, size_t aZ, size_t bZ, size_t oZ)
{
  constexpr int ABUF = 128 * 32;
  constexpr int BBUF = BN * 32;
  __shared__ bf16 As[2 * ABUF];
  __shared__ bf16 Bs[2 * BBUF];
  const int z = blockIdx.z;
  A += (size_t)z * aZ;
  B += (size_t)z * bZ;
  const int kbeg = z * kZ;
  const int tid  = threadIdx.x;
  const int lane = tid & 63, wave = tid >> 6;

  // Bijective XCD-chunked tile remap (m204 general form; works for nwg%8!=0).
  // Consecutive remapped ids share the A m-panel (n-fastest decode), so each
  // XCD's chunk re-reads one small A slice against (nearly) all B panels.
  const int nx = gridDim.x, ny = gridDim.y;
  const int nwg = nx * ny;
  const int f0 = blockIdx.y * nx + blockIdx.x;      // dispatch order (x fastest)
  const int xcd = f0 & 7, idx = f0 >> 3;
  const int q8 = nwg >> 3, r8 = nwg & 7;
  const int f = (xcd < r8 ? xcd * (q8 + 1) : r8 * (q8 + 1) + (xcd - r8) * q8) + idx;
  const int m0 = (f / ny) * 128, n0 = (f % ny) * BN;

  // Staging: thread tid covers row r = tid>>2, physical slot tid&3.
  // Global chunk for that slot: kq = ((tid&3) - (r>>1)) & 3 — a permutation
  // within one aligned 64B line, so coalescing is preserved.
  const int r  = tid >> 2;
  const int kq = ((tid & 3) - (tid >> 3)) & 3;
  const bf16* aG0 = A + (size_t)(m0 + r) * K + kq * 8 + kbeg;
  const bf16* aG1 = aG0 + (size_t)64 * K;
  const bf16* bG0 = B + (size_t)(n0 + r) * K + kq * 8 + kbeg;
  const bf16* bG1 = bG0 + (size_t)64 * K;   // used only for BN==128

  const int wr = (wave & 1) * 64, wc = (wave >> 1) * (BN / 2);
  const int lr = lane & 15, kb = lane >> 4;
  const int swz  = ((kb + (lr >> 1)) & 3) * 8;
  const int aOff = (wr + lr) * 32 + swz;
  const int bOff = (wc + lr) * 32 + swz;

  constexpr int MT = 4, NT = BN / 32;
  f32x4 acc[MT][NT] = {};
  const int iters = klen >> 5;

  auto stage = [&](int p, int k0) {
    bf16* aD = &As[p * ABUF + tid * 8];
    gload16(aG0 + k0, aD);
    gload16(aG1 + k0, aD + 2048);
    bf16* bD = &Bs[p * BBUF + tid * 8];
    gload16(bG0 + k0, bD);
    if (BN == 128) gload16(bG1 + k0, bD + 2048);
  };

  stage(0, 0);
  for (int it = 0; it < iters; ++it) {
    __syncthreads();                       // drains own vmcnt (tile it landed) + lgkm
    if (it + 1 < iters) stage((it + 1) & 1, (it + 1) * 32);  // overlaps MFMA below
    const int pa = (it & 1) * ABUF, pb = (it & 1) * BBUF;
    bf16x8 af[MT], bfv[NT];
#pragma unroll
    for (int t = 0; t < MT; ++t) af[t] = *(const bf16x8*)&As[pa + aOff + t * 512];
#pragma unroll
    for (int t = 0; t < NT; ++t) bfv[t] = *(const bf16x8*)&Bs[pb + bOff + t * 512];
#pragma unroll
    for (int mt = 0; mt < MT; ++mt)
#pragma unroll
      for (int nt = 0; nt < NT; ++nt)
        acc[mt][nt] = __builtin_amdgcn_mfma_f32_16x16x32_bf16(af[mt], bfv[nt], acc[mt][nt], 0, 0, 0);
  }

  // C/D layout: col = lane&15, row = (lane>>4)*4 + reg  [verified m89/m91]
  const int row0 = m0 + wr + (lane >> 4) * 4;
  const int col0 = n0 + wc + lr;
  float* oF = (EPI == EPI_PART) ? outF + (size_t)z * oZ : nullptr;
  bf16*  oB = (EPI == EPI_B16)  ? outB + (size_t)z * oZ : outB;
#pragma unroll
  for (int mt = 0; mt < MT; ++mt) {
#pragma unroll
    for (int nt = 0; nt < NT; ++nt) {
      const int col = col0 + nt * 16;
      float bias = 0.f;
      if (EPI == EPI_GELU) bias = aux[col];
#pragma unroll
      for (int rg = 0; rg < 4; ++rg) {
        const int row = row0 + mt * 16 + rg;
        float v = acc[mt][nt][rg];
        if (EPI == EPI_PART) {
          oF[(size_t)row * N + col] = v;
        } else if (EPI == EPI_GELU) {
          oB[(size_t)row * N + col] = (bf16)gelu_f(v + bias);
        } else {
          oB[(size_t)row * N + col] = (bf16)v;
        }
      }
    }
  }
}

// One 768-row per block; sums NP split-K partials, adds per-MODE term, LN-fuses.
// MODE 0: s = Σp + PE[row&255]; T=s; SN = LN1(s)
// MODE 1: s = Σp + add[row]   ; SN = LN2(s)+s
// MODE 2: s = Σp + bias       ; T=s; SN = LN1(s)
// MODE 3: s = Σp + bias       ; T=s (fp32 out only, last stage)
template <int NP, int MODE>
__global__ __launch_bounds__(256) void reduce_ln(
    const float* __restrict__ P, size_t pZ,
    const float* __restrict__ add, const float* __restrict__ g,
    const float* __restrict__ b, float* __restrict__ Tout,
    bf16* __restrict__ SNout)
{
  const int row = blockIdx.x, t = threadIdx.x;
  float v[3];
#pragma unroll
  for (int c = 0; c < 3; ++c) {
    const int col = t + c * 256;
    float s = P[(size_t)row * 768 + col];
#pragma unroll
    for (int p = 1; p < NP; ++p) s += P[(size_t)p * pZ + (size_t)row * 768 + col];
    if (MODE == 0) s += add[(row & 255) * 768 + col];
    if (MODE == 1) s += add[(size_t)row * 768 + col];
    if (MODE == 2 || MODE == 3) s += add[col];
    v[c] = s;
  }
  if (MODE != 1) {
#pragma unroll
    for (int c = 0; c < 3; ++c) Tout[(size_t)row * 768 + t + c * 256] = v[c];
  }
  if (MODE == 3) return;

  __shared__ float red[8];
  float s = v[0] + v[1] + v[2];
#pragma unroll
  for (int o = 32; o >= 1; o >>= 1) s += __shfl_down(s, o);
  if ((t & 63) == 0) red[t >> 6] = s;
  __syncthreads();
  const float mu = (red[0] + red[1] + red[2] + red[3]) * (1.f / 768.f);
  const float d0 = v[0] - mu, d1 = v[1] - mu, d2 = v[2] - mu;
  float q = d0 * d0 + d1 * d1 + d2 * d2;
#pragma unroll
  for (int o = 32; o >= 1; o >>= 1) q += __shfl_down(q, o);
  if ((t & 63) == 0) red[4 + (t >> 6)] = q;
  __syncthreads();
  const float var = (red[4] + red[5] + red[6] + red[7]) * (1.f / 768.f);
  const float rs = rsqrtf(var + 1e-5f);
  float y0 = d0 * rs * g[t] + b[t];
  float y1 = d1 * rs * g[t + 256] + b[t + 256];
  float y2 = d2 * rs * g[t + 512] + b[t + 512];
  if (MODE == 1) { y0 += v[0]; y1 += v[1]; y2 += v[2]; }
  bf16* o = SNout + (size_t)row * 768;
  o[t] = (bf16)y0; o[t + 256] = (bf16)y1; o[t + 512] = (bf16)y2;
}

// Exclusive prefix over token axis j (256 tokens) of SN[n,j,d], bf16 io.
__global__ __launch_bounds__(256) void scan_partial_b(
    const bf16* __restrict__ SN, float* __restrict__ Ps)
{
  const int n = blockIdx.x, ch = blockIdx.y, d = blockIdx.z * 256 + threadIdx.x;
  const bf16* base = SN + ((size_t)(n * 256 + ch * 16)) * 768 + d;
  float s = 0.f;
#pragma unroll
  for (int j = 0; j < 16; ++j) s += (float)base[(size_t)j * 768];
  Ps[(size_t)(n * 16 + ch) * 768 + d] = s;
}

__global__ __launch_bounds__(256) void scan_final_b(
    const bf16* __restrict__ SN, const float* __restrict__ Ps,
    bf16* __restrict__ PSb)
{
  const int n = blockIdx.x, ch = blockIdx.y, d = blockIdx.z * 256 + threadIdx.x;
  float run = 0.f;
  for (int c = 0; c < ch; ++c) run += Ps[(size_t)(n * 16 + c) * 768 + d];
  const bf16* vb = SN + ((size_t)(n * 256 + ch * 16)) * 768 + d;
  bf16* ob = PSb + ((size_t)(n * 256 + ch * 16)) * 768 + d;
#pragma unroll
  for (int j = 0; j < 16; ++j) {
    ob[(size_t)j * 768] = (bf16)run;
    run += (float)vb[(size_t)j * 768];
  }
}

// WvT[a][n][k] = (bf16)Wv[a][k][n]; 64x64 tiles via LDS (65-float stride).
__global__ __launch_bounds__(256) void transpose_wv(
    const float* __restrict__ Wv, bf16* __restrict__ WvT)
{
  __shared__ float tile[64][65];
  const int a = blockIdx.z, k0 = blockIdx.x * 64, n0 = blockIdx.y * 64;
  const int c = threadIdx.x & 63, r4 = threadIdx.x >> 6;
  const float* src = Wv + (size_t)a * 589824;
  bf16* dst = WvT + (size_t)a * 589824;
#pragma unroll
  for (int i = 0; i < 16; ++i)
    tile[r4 + i * 4][c] = src[(size_t)(k0 + r4 + i * 4) * 768 + n0 + c];
  __syncthreads();
#pragma unroll
  for (int i = 0; i < 16; ++i) {
    const int n = r4 + i * 4;
    dst[(size_t)(n0 + n) * 768 + k0 + c] = (bf16)tile[c][n];
  }
}

__global__ __launch_bounds__(256) void f32_to_bf16_k(
    const float* __restrict__ in, bf16* __restrict__ out, int n4)
{
  const int i = blockIdx.x * 256 + threadIdx.x;
  if (i >= n4) return;
  const float4 v = ((const float4*)in)[i];
  bf16 h[4] = {(bf16)v.x, (bf16)v.y, (bf16)v.z, (bf16)v.w};
  *(uint2*)(out + 4 * (size_t)i) = *(uint2*)h;
}

// pe[j, 2p] = sin(j / 10000^(4p/768)),  pe[j, 2p+1] = cos(...)
__global__ __launch_bounds__(256) void pe_kernel(float* __restrict__ PE)
{
  const int id = blockIdx.x * 256 + threadIdx.x;  // 256*384 total
  const int j = id / 384, p = id % 384;
  const double ang = (double)j * pow(10000.0, -4.0 * (double)p / 768.0);
  PE[(size_t)j * 768 + 2 * p]     = (float)sin(ang);
  PE[(size_t)j * 768 + 2 * p + 1] = (float)cos(ang);
}

extern "C" void kernel_launch(void* const* d_in, const int* in_sizes, int n_in,
                              void* d_out, int out_size, void* d_ws, size_t ws_size,
                              hipStream_t stream)
{
  const float* x      = (const float*)d_in[0];
  const float* weight = (const float*)d_in[1];
  const float* Wv     = (const float*)d_in[4];
  const float* Wo     = (const float*)d_in[5];
  const float* ln1g   = (const float*)d_in[6];
  const float* ln1b   = (const float*)d_in[7];
  const float* ln2g   = (const float*)d_in[8];
  const float* ln2b   = (const float*)d_in[9];
  const float* fc1w   = (const float*)d_in[10];
  const float* fc1b   = (const float*)d_in[11];
  const float* fc2w   = (const float*)d_in[12];
  const float* fc2b   = (const float*)d_in[13];
  float* out = (float*)d_out;

  char* p = (char*)d_ws;
  auto alloc = [&](size_t bytes) { char* r = p; p += (bytes + 255) & ~(size_t)255; return r; };
  bf16*  Wb_w  = (bf16*)alloc(589824ull * 2);
  bf16*  Wb_o  = (bf16*)alloc(5898240ull * 2);
  bf16*  WvT   = (bf16*)alloc(5898240ull * 2);
  bf16*  Wvo   = (bf16*)alloc(5898240ull * 2);
  bf16*  Wb_f1 = (bf16*)alloc(2359296ull * 2);
  bf16*  Wb_f2 = (bf16*)alloc(2359296ull * 2);
  bf16*  Xb    = (bf16*)alloc(3145728ull * 2);
  float* PEf   = (float*)alloc(196608ull * 4);
  float* T     = (float*)alloc(3145728ull * 4);
  bf16*  SN    = (bf16*)alloc(3145728ull * 2);
  bf16*  PSb   = (bf16*)alloc(3145728ull * 2);
  bf16*  H     = (bf16*)alloc(12582912ull * 2);
  float* Ps    = (float*)alloc(196608ull * 4);
  float* Part  = (float*)alloc(4ull * 3145728ull * 4);   // 4 split-K partials (fc2)

  auto cvt = [&](const float* src, bf16* dst, int n) {
    int n4 = n / 4;
    f32_to_bf16_k<<<(n4 + 255) / 256, 256, 0, stream>>>(src, dst, n4);
  };
  cvt(x, Xb, 3145728);
  cvt(weight, Wb_w, 589824);
  cvt(Wo, Wb_o, 5898240);
  cvt(fc1w, Wb_f1, 2359296);
  cvt(fc2w, Wb_f2, 2359296);
  transpose_wv<<<dim3(12, 12, 10), 256, 0, stream>>>(Wv, WvT);
  pe_kernel<<<384, 256, 0, stream>>>(PEf);

  // Wvo[a] = Wo[a] @ Wv[a]  (A = Wo[a][m,t], B = WvT[a][k,t], batched over z)
  gemm_k<128, EPI_B16><<<dim3(6, 6, 10), 256, 0, stream>>>(
      Wb_o, WvT, nullptr, Wvo, nullptr, 768, 768, 0, 768, 589824, 589824, 589824);

  // T0 = x @ weight^T + PE (split-K x2, 128x64 tiles), fused LN1
  gemm_k<64, EPI_PART><<<dim3(32, 12, 2), 256, 0, stream>>>(
      Xb, Wb_w, Part, nullptr, nullptr, 768, 768, 384, 384, 0, 0, 3145728);
  reduce_ln<2, 0><<<4096, 256, 0, stream>>>(Part, 3145728, PEf, ln1g, ln1b, T, SN);

  for (int a = 0; a < 10; ++a) {
    scan_partial_b<<<dim3(16, 16, 3), 256, 0, stream>>>(SN, Ps);
    scan_final_b<<<dim3(16, 16, 3), 256, 0, stream>>>(SN, Ps, PSb);
    // S1 partials = PS @ Wvo[a]^T  (split-K x2, 128x64 tiles)
    gemm_k<64, EPI_PART><<<dim3(32, 12, 2), 256, 0, stream>>>(
        PSb, Wvo + (size_t)a * 589824, Part, nullptr, nullptr, 768, 768, 384, 384, 0, 0, 3145728);
    reduce_ln<2, 1><<<4096, 256, 0, stream>>>(Part, 3145728, T, ln2g, ln2b, nullptr, SN);
    // fc1: H = gelu(SN2 @ fc1w^T + b) — BN=64, grid 32x48 = 1536 blocks (6/CU)
    gemm_k<64, EPI_GELU><<<dim3(32, 48, 1), 256, 0, stream>>>(
        SN, Wb_f1, nullptr, H, fc1b, 768, 3072, 0, 768, 0, 0, 0);
    // fc2 partials: H @ fc2w^T — split-K x4, grid 32x12x4 = 1536 blocks (6/CU)
    gemm_k<64, EPI_PART><<<dim3(32, 12, 4), 256, 0, stream>>>(
        H, Wb_f2, Part, nullptr, nullptr, 3072, 768, 768, 768, 0, 0, 3145728);
    if (a < 9)
      reduce_ln<4, 2><<<4096, 256, 0, stream>>>(Part, 3145728, fc2b, ln1g, ln1b, T, SN);
    else
      reduce_ln<4, 3><<<4096, 256, 0, stream>>>(Part, 3145728, fc2b, nullptr, nullptr, out, nullptr);
  }
  (void)in_sizes; (void)n_in; (void)out_size; (void)ws_size;
}

// Round 5
// 1290.833 us; speedup vs baseline: 1.1082x; 1.1082x over previous
//
#include <hip/hip_runtime.h>
#include <hip/hip_bf16.h>
#include <math.h>

// RTM identities:
//  - softmax over size-1 axis == 1  =>  q,k,Wq,Wk dead; newV == v
//  - token j restarts from s0[:,j]; only cumV couples tokens
//  - prefix-sum linear => fold Wv into Wo: Wvo[a] = Wo[a] @ Wv[a] (once);
//       S1 = PS(LN1(T)) @ Wvo[a]^T + T
// R8 (8-phase w/ register-prefetched next-tile frags) FAILED correctness:
// ~290 live VGPR > 256 cap -> scratch spills -> spill buffer_load/store
// increment vmcnt -> counted s_waitcnt vmcnt(4) ledger corrupted -> LDS read
// before DMA landed. R9: faithful m201 template — PHASE-LOCAL ds_reads
// (read the quadrant consumed this phase), ~215 VGPR, no spills, ledger sound.
// Per K-tile u (slot s=u&1), 4 phases:
//   p1: rdA(q0)+rdB | stA(s^1,0,u+1) | bar lgkm0 schedbar prio MFMA q0 bar
//   p2: rdA(q1)     | stA(s^1,1,u+1) | bar lgkm0 schedbar prio MFMA q1 bar
//   p3: rdA(q2)     | stB(s,0,u+2)   | bar lgkm0 schedbar prio MFMA q2 bar
//   p4: rdA(q3)     | stB(s,1,u+2)   | bar lgkm0 schedbar prio MFMA q3
//       vmcnt(4) [tile u+1 fully landed; B(u+2) in flight] bar
// Region safety: Bs[s] re-staged p3/p4, last read p1 (lgkm0+barrier before);
// As[s^1] re-staged p1/p2, last read p4 of tile u-1. Reads of tile u+1 at
// p1(u+1) gated by vmcnt(4)+barrier at p4(u).

using bf16   = __bf16;
using bf16x8 = __attribute__((ext_vector_type(8))) __bf16;
using f32x4  = __attribute__((ext_vector_type(4))) float;

#define DEV __device__ __forceinline__

DEV void gload16(const bf16* g, bf16* l) {
  __builtin_amdgcn_global_load_lds(
      (const __attribute__((address_space(1))) unsigned int*)g,
      (__attribute__((address_space(3))) unsigned int*)l, 16, 0, 0);
}

// GELU with A&S 7.1.26 erf (abs err 1.5e-7; << bf16 rounding).
DEV float gelu_f(float x) {
  const float y  = x * 0.70710678118654752f;
  const float ay = fabsf(y);
  const float t  = __builtin_amdgcn_rcpf(__builtin_fmaf(0.3275911f, ay, 1.0f));
  float p = __builtin_fmaf(1.061405429f, t, -1.453152027f);
  p = __builtin_fmaf(p, t, 1.421413741f);
  p = __builtin_fmaf(p, t, -0.284496736f);
  p = __builtin_fmaf(p, t, 0.254829592f);
  p = p * t;
  const float e = __expf(-ay * ay);
  float er = __builtin_fmaf(-p, e, 1.0f);
  er = __builtin_copysignf(er, y);
  return 0.5f * x * (1.0f + er);
}

enum { EPI_PART = 0, EPI_GELU = 1, EPI_B16 = 2 };

#define BARRIER() do { asm volatile("" ::: "memory");                        \
  __builtin_amdgcn_s_barrier(); asm volatile("" ::: "memory"); } while (0)
#define LGKM0_FENCE() do {                                                   \
  asm volatile("s_waitcnt lgkmcnt(0)" ::: "memory");                         \
  __builtin_amdgcn_sched_barrier(0); } while (0)

// 256x256-tile 8-phase GEMM: C = A[M,K] @ B[N,K]^T on K-slice z.
// 512 thr = 8 waves (wr=w>>2 row-half, wc=w&3 col-quarter); per-wave 128x64.
// LDS: As/Bs[2 slots][2 halves][128x64] bf16 = 128 KiB. Swizzle: physical
// 16B chunk p of local row r holds global chunk (p-r)&7; staging pre-swizzles
// the GLOBAL source (LDS dest linear for global_load_lds); reads use
// p=(kc+r)&7 (both-sides-or-neither, rule #21).
template <int EPI>
__global__ __launch_bounds__(512, 2) void gemm256(
    const bf16* __restrict__ A, const bf16* __restrict__ B,
    float* __restrict__ outF, bf16* __restrict__ outB,
    const float* __restrict__ aux, int K, int N,
    int kZ, int klen, size_t oZ)
{
  __shared__ bf16 As[2][2][8192];
  __shared__ bf16 Bs[2][2][8192];
  const int z = blockIdx.z;
  const int kbeg = z * kZ;
  const int NT = klen >> 6;                   // K-tiles of 64
  const int tid = threadIdx.x, lane = tid & 63, w = tid >> 6;
  const int wr = w >> 2, wc = w & 3;
  const int lr = lane & 15, kb = lane >> 4;
  const int bh = wc >> 1, bcol0 = (wc & 1) * 64;
  const int rst = tid >> 3, kcst = ((tid & 7) - (tid >> 3)) & 7;

  // Bijective XCD-chunked tile remap (grids are multiples of 8).
  const int nx = gridDim.x;
  const int nwg = nx * (int)gridDim.y;
  int f = blockIdx.x + nx * blockIdx.y;
  const int xcd = f & 7, idx = f >> 3;
  const int q8 = nwg >> 3, r8 = nwg & 7;
  f = (xcd < r8 ? xcd * (q8 + 1) : r8 * (q8 + 1) + (xcd - r8) * q8) + idx;
  const int m0 = (f % nx) * 256, n0 = (f / nx) * 256;

  const bf16* aG[2] = { A + (size_t)(m0 + rst) * K + kbeg + kcst * 8,
                        A + (size_t)(m0 + 128 + rst) * K + kbeg + kcst * 8 };
  const bf16* bG[2] = { B + (size_t)(n0 + rst) * K + kbeg + kcst * 8,
                        B + (size_t)(n0 + 128 + rst) * K + kbeg + kcst * 8 };

  f32x4 acc[8][4] = {};
  bf16x8 av[4], bv[8];

  auto stA = [&](int slot, int h, int t) {
    bf16* d = &As[slot][h][0] + tid * 8;
    const bf16* g = aG[h] + t * 64;
    gload16(g, d); gload16(g + (size_t)64 * K, d + 4096);
  };
  auto stB = [&](int slot, int h, int t) {
    bf16* d = &Bs[slot][h][0] + tid * 8;
    const bf16* g = bG[h] + t * 64;
    gload16(g, d); gload16(g + (size_t)64 * K, d + 4096);
  };
  auto rdA = [&](int s, int q) {
#pragma unroll
    for (int j = 0; j < 2; ++j)
#pragma unroll
      for (int k = 0; k < 2; ++k) {
        const int row = (2 * q + j) * 16 + lr;
        const int p = ((k * 4 + kb) + (lr & 7)) & 7;
        av[j * 2 + k] = *(const bf16x8*)&As[s][wr][row * 64 + p * 8];
      }
  };
  auto rdB = [&](int s) {
#pragma unroll
    for (int nt = 0; nt < 4; ++nt)
#pragma unroll
      for (int k = 0; k < 2; ++k) {
        const int row = bcol0 + nt * 16 + lr;
        const int p = ((k * 4 + kb) + (lr & 7)) & 7;
        bv[nt * 2 + k] = *(const bf16x8*)&Bs[s][bh][row * 64 + p * 8];
      }
  };
  auto mfmaQ = [&](int q) {
    __builtin_amdgcn_s_setprio(1);
#pragma unroll
    for (int nt = 0; nt < 4; ++nt)
#pragma unroll
      for (int j = 0; j < 2; ++j)
#pragma unroll
        for (int k = 0; k < 2; ++k)
          acc[2 * q + j][nt] = __builtin_amdgcn_mfma_f32_16x16x32_bf16(
              av[j * 2 + k], bv[nt * 2 + k], acc[2 * q + j][nt], 0, 0, 0);
    __builtin_amdgcn_s_setprio(0);
  };

  // Prologue: tile 0 complete + B of tile 1; wait tile 0 only (counted).
  stA(0, 0, 0); stA(0, 1, 0); stB(0, 0, 0); stB(0, 1, 0);
  if (NT > 1) { stB(1, 0, 1); stB(1, 1, 1); }
  if (NT > 1) asm volatile("s_waitcnt vmcnt(4)" ::: "memory");
  else        asm volatile("s_waitcnt vmcnt(0)" ::: "memory");
  BARRIER();

  for (int u = 0; u < NT; ++u) {
    const int s = u & 1;
    const bool g1 = u + 1 < NT, g2 = u + 2 < NT;
    // p1
    rdA(s, 0); rdB(s);
    if (g1) stA(s ^ 1, 0, u + 1);
    BARRIER();
    LGKM0_FENCE();
    mfmaQ(0);
    BARRIER();
    // p2
    rdA(s, 1);
    if (g1) stA(s ^ 1, 1, u + 1);
    BARRIER();
    LGKM0_FENCE();
    mfmaQ(1);
    BARRIER();
    // p3
    rdA(s, 2);
    if (g2) stB(s, 0, u + 2);
    BARRIER();
    LGKM0_FENCE();
    mfmaQ(2);
    BARRIER();
    // p4
    rdA(s, 3);
    if (g2) stB(s, 1, u + 2);
    BARRIER();
    LGKM0_FENCE();
    mfmaQ(3);
    if (g2)      asm volatile("s_waitcnt vmcnt(4)" ::: "memory");
    else if (g1) asm volatile("s_waitcnt vmcnt(0)" ::: "memory");
    BARRIER();
  }

  // C/D layout: col = lane&15, row = (lane>>4)*4 + reg  [verified m89/m91]
  const int row0 = m0 + wr * 128 + (lane >> 4) * 4;
  const int col0 = n0 + wc * 64 + lr;
  float* oF = (EPI == EPI_PART) ? outF + (size_t)z * oZ : nullptr;
#pragma unroll
  for (int mt = 0; mt < 8; ++mt) {
#pragma unroll
    for (int nt = 0; nt < 4; ++nt) {
      const int col = col0 + nt * 16;
      float bias = 0.f;
      if (EPI == EPI_GELU) bias = aux[col];
#pragma unroll
      for (int rg = 0; rg < 4; ++rg) {
        const int row = row0 + mt * 16 + rg;
        float v = acc[mt][nt][rg];
        if (EPI == EPI_PART) {
          oF[(size_t)row * N + col] = v;
        } else {
          outB[(size_t)row * N + col] = (bf16)gelu_f(v + bias);
        }
      }
    }
  }
}

// ---- 128xBN-tile GEMM — exact R0-proven 2-buf loop (small GEMMs) -----------
template <int BN, int EPI>
__global__ __launch_bounds__(256) void gemm_k(
    const bf16* __restrict__ A, const bf16* __restrict__ B,
    float* __restrict__ outF, bf16* __restrict__ outB,
    const float* __restrict__ aux, int K, int N,
    int kZ, int klen, size_t aZ, size_t bZ, size_t oZ)
{
  constexpr int ABUF = 128 * 32;
  constexpr int BBUF = BN * 32;
  __shared__ bf16 Asl[2 * ABUF];
  __shared__ bf16 Bsl[2 * BBUF];
  const int z = blockIdx.z;
  A += (size_t)z * aZ;
  B += (size_t)z * bZ;
  const int kbeg = z * kZ;
  const int tid  = threadIdx.x;
  const int lane = tid & 63, wave = tid >> 6;
  const int m0 = blockIdx.x * 128, n0 = blockIdx.y * BN;

  const int r  = tid >> 2;
  const int kq = ((tid & 3) - (tid >> 3)) & 3;
  const bf16* aG0 = A + (size_t)(m0 + r) * K + kq * 8 + kbeg;
  const bf16* aG1 = aG0 + (size_t)64 * K;
  const bf16* bG0 = B + (size_t)(n0 + r) * K + kq * 8 + kbeg;
  const bf16* bG1 = bG0 + (size_t)64 * K;   // used only for BN==128

  const int wr = (wave & 1) * 64, wc = (wave >> 1) * (BN / 2);
  const int lr = lane & 15, kb = lane >> 4;
  const int swz  = ((kb + (lr >> 1)) & 3) * 8;
  const int aOff = (wr + lr) * 32 + swz;
  const int bOff = (wc + lr) * 32 + swz;

  constexpr int MT = 4, NTT = BN / 32;
  f32x4 acc[MT][NTT] = {};
  const int iters = klen >> 5;

  auto stage = [&](int p, int k0) {
    bf16* aD = &Asl[p * ABUF + tid * 8];
    gload16(aG0 + k0, aD);
    gload16(aG1 + k0, aD + 2048);
    bf16* bD = &Bsl[p * BBUF + tid * 8];
    gload16(bG0 + k0, bD);
    if (BN == 128) gload16(bG1 + k0, bD + 2048);
  };

  stage(0, 0);
  for (int it = 0; it < iters; ++it) {
    __syncthreads();
    if (it + 1 < iters) stage((it + 1) & 1, (it + 1) * 32);
    const int pa = (it & 1) * ABUF, pb = (it & 1) * BBUF;
    bf16x8 af[MT], bfv[NTT];
#pragma unroll
    for (int t = 0; t < MT; ++t) af[t] = *(const bf16x8*)&Asl[pa + aOff + t * 512];
#pragma unroll
    for (int t = 0; t < NTT; ++t) bfv[t] = *(const bf16x8*)&Bsl[pb + bOff + t * 512];
#pragma unroll
    for (int mt = 0; mt < MT; ++mt)
#pragma unroll
      for (int nt = 0; nt < NTT; ++nt)
        acc[mt][nt] = __builtin_amdgcn_mfma_f32_16x16x32_bf16(af[mt], bfv[nt], acc[mt][nt], 0, 0, 0);
  }

  const int row0 = m0 + wr + (lane >> 4) * 4;
  const int col0 = n0 + wc + lr;
  float* oF = (EPI == EPI_PART) ? outF + (size_t)z * oZ : nullptr;
  bf16*  oB = (EPI == EPI_B16)  ? outB + (size_t)z * oZ : outB;
#pragma unroll
  for (int mt = 0; mt < MT; ++mt) {
#pragma unroll
    for (int nt = 0; nt < NTT; ++nt) {
      const int col = col0 + nt * 16;
      float bias = 0.f;
      if (EPI == EPI_GELU) bias = aux[col];
#pragma unroll
      for (int rg = 0; rg < 4; ++rg) {
        const int row = row0 + mt * 16 + rg;
        float v = acc[mt][nt][rg];
        if (EPI == EPI_PART) {
          oF[(size_t)row * N + col] = v;
        } else if (EPI == EPI_GELU) {
          oB[(size_t)row * N + col] = (bf16)gelu_f(v + bias);
        } else {
          oB[(size_t)row * N + col] = (bf16)v;
        }
      }
    }
  }
}

// One 768-row per block; sums NP split-K partials, adds per-MODE term, LN-fuses.
// MODE 0: s = Σp + PE[row&255]; T=s; SN = LN1(s)
// MODE 1: s = Σp + add[row]   ; SN = LN2(s)+s
// MODE 2: s = Σp + bias       ; T=s; SN = LN1(s)
// MODE 3: s = Σp + bias       ; T=s (fp32 out only, last stage)
template <int NP, int MODE>
__global__ __launch_bounds__(256) void reduce_ln(
    const float* __restrict__ P, size_t pZ,
    const float* __restrict__ add, const float* __restrict__ g,
    const float* __restrict__ b, float* __restrict__ Tout,
    bf16* __restrict__ SNout)
{
  const int row = blockIdx.x, t = threadIdx.x;
  float v[3];
#pragma unroll
  for (int c = 0; c < 3; ++c) {
    const int col = t + c * 256;
    float s = P[(size_t)row * 768 + col];
#pragma unroll
    for (int p = 1; p < NP; ++p) s += P[(size_t)p * pZ + (size_t)row * 768 + col];
    if (MODE == 0) s += add[(row & 255) * 768 + col];
    if (MODE == 1) s += add[(size_t)row * 768 + col];
    if (MODE == 2 || MODE == 3) s += add[col];
    v[c] = s;
  }
  if (MODE != 1) {
#pragma unroll
    for (int c = 0; c < 3; ++c) Tout[(size_t)row * 768 + t + c * 256] = v[c];
  }
  if (MODE == 3) return;

  __shared__ float red[8];
  float s = v[0] + v[1] + v[2];
#pragma unroll
  for (int o = 32; o >= 1; o >>= 1) s += __shfl_down(s, o);
  if ((t & 63) == 0) red[t >> 6] = s;
  __syncthreads();
  const float mu = (red[0] + red[1] + red[2] + red[3]) * (1.f / 768.f);
  const float d0 = v[0] - mu, d1 = v[1] - mu, d2 = v[2] - mu;
  float q = d0 * d0 + d1 * d1 + d2 * d2;
#pragma unroll
  for (int o = 32; o >= 1; o >>= 1) q += __shfl_down(q, o);
  if ((t & 63) == 0) red[4 + (t >> 6)] = q;
  __syncthreads();
  const float var = (red[4] + red[5] + red[6] + red[7]) * (1.f / 768.f);
  const float rs = rsqrtf(var + 1e-5f);
  float y0 = d0 * rs * g[t] + b[t];
  float y1 = d1 * rs * g[t + 256] + b[t + 256];
  float y2 = d2 * rs * g[t + 512] + b[t + 512];
  if (MODE == 1) { y0 += v[0]; y1 += v[1]; y2 += v[2]; }
  bf16* o = SNout + (size_t)row * 768;
  o[t] = (bf16)y0; o[t + 256] = (bf16)y1; o[t + 512] = (bf16)y2;
}

// Exclusive prefix over token axis j (256 tokens) of SN[n,j,d], bf16 io.
__global__ __launch_bounds__(256) void scan_partial_b(
    const bf16* __restrict__ SN, float* __restrict__ Ps)
{
  const int n = blockIdx.x, ch = blockIdx.y, d = blockIdx.z * 256 + threadIdx.x;
  const bf16* base = SN + ((size_t)(n * 256 + ch * 16)) * 768 + d;
  float s = 0.f;
#pragma unroll
  for (int j = 0; j < 16; ++j) s += (float)base[(size_t)j * 768];
  Ps[(size_t)(n * 16 + ch) * 768 + d] = s;
}

__global__ __launch_bounds__(256) void scan_final_b(
    const bf16* __restrict__ SN, const float* __restrict__ Ps,
    bf16* __restrict__ PSb)
{
  const int n = blockIdx.x, ch = blockIdx.y, d = blockIdx.z * 256 + threadIdx.x;
  float run = 0.f;
  for (int c = 0; c < ch; ++c) run += Ps[(size_t)(n * 16 + c) * 768 + d];
  const bf16* vb = SN + ((size_t)(n * 256 + ch * 16)) * 768 + d;
  bf16* ob = PSb + ((size_t)(n * 256 + ch * 16)) * 768 + d;
#pragma unroll
  for (int j = 0; j < 16; ++j) {
    ob[(size_t)j * 768] = (bf16)run;
    run += (float)vb[(size_t)j * 768];
  }
}

// WvT[a][n][k] = (bf16)Wv[a][k][n]; 64x64 tiles via LDS (65-float stride).
__global__ __launch_bounds__(256) void transpose_wv(
    const float* __restrict__ Wv, bf16* __restrict__ WvT)
{
  __shared__ float tile[64][65];
  const int a = blockIdx.z, k0 = blockIdx.x * 64, n0 = blockIdx.y * 64;
  const int c = threadIdx.x & 63, r4 = threadIdx.x >> 6;
  const float* src = Wv + (size_t)a * 589824;
  bf16* dst = WvT + (size_t)a * 589824;
#pragma unroll
  for (int i = 0; i < 16; ++i)
    tile[r4 + i * 4][c] = src[(size_t)(k0 + r4 + i * 4) * 768 + n0 + c];
  __syncthreads();
#pragma unroll
  for (int i = 0; i < 16; ++i) {
    const int n = r4 + i * 4;
    dst[(size_t)(n0 + n) * 768 + k0 + c] = (bf16)tile[c][n];
  }
}

__global__ __launch_bounds__(256) void f32_to_bf16_k(
    const float* __restrict__ in, bf16* __restrict__ out, int n4)
{
  const int i = blockIdx.x * 256 + threadIdx.x;
  if (i >= n4) return;
  const float4 v = ((const float4*)in)[i];
  bf16 h[4] = {(bf16)v.x, (bf16)v.y, (bf16)v.z, (bf16)v.w};
  *(uint2*)(out + 4 * (size_t)i) = *(uint2*)h;
}

// pe[j, 2p] = sin(j / 10000^(4p/768)),  pe[j, 2p+1] = cos(...)
__global__ __launch_bounds__(256) void pe_kernel(float* __restrict__ PE)
{
  const int id = blockIdx.x * 256 + threadIdx.x;  // 256*384 total
  const int j = id / 384, p = id % 384;
  const double ang = (double)j * pow(10000.0, -4.0 * (double)p / 768.0);
  PE[(size_t)j * 768 + 2 * p]     = (float)sin(ang);
  PE[(size_t)j * 768 + 2 * p + 1] = (float)cos(ang);
}

extern "C" void kernel_launch(void* const* d_in, const int* in_sizes, int n_in,
                              void* d_out, int out_size, void* d_ws, size_t ws_size,
                              hipStream_t stream)
{
  const float* x      = (const float*)d_in[0];
  const float* weight = (const float*)d_in[1];
  const float* Wv     = (const float*)d_in[4];
  const float* Wo     = (const float*)d_in[5];
  const float* ln1g   = (const float*)d_in[6];
  const float* ln1b   = (const float*)d_in[7];
  const float* ln2g   = (const float*)d_in[8];
  const float* ln2b   = (const float*)d_in[9];
  const float* fc1w   = (const float*)d_in[10];
  const float* fc1b   = (const float*)d_in[11];
  const float* fc2w   = (const float*)d_in[12];
  const float* fc2b   = (const float*)d_in[13];
  float* out = (float*)d_out;

  char* p = (char*)d_ws;
  auto alloc = [&](size_t bytes) { char* r = p; p += (bytes + 255) & ~(size_t)255; return r; };
  bf16*  Wb_w  = (bf16*)alloc(589824ull * 2);
  bf16*  Wb_o  = (bf16*)alloc(5898240ull * 2);
  bf16*  WvT   = (bf16*)alloc(5898240ull * 2);
  bf16*  Wvo   = (bf16*)alloc(5898240ull * 2);
  bf16*  Wb_f1 = (bf16*)alloc(2359296ull * 2);
  bf16*  Wb_f2 = (bf16*)alloc(2359296ull * 2);
  bf16*  Xb    = (bf16*)alloc(3145728ull * 2);
  float* PEf   = (float*)alloc(196608ull * 4);
  float* T     = (float*)alloc(3145728ull * 4);
  bf16*  SN    = (bf16*)alloc(3145728ull * 2);
  bf16*  PSb   = (bf16*)alloc(3145728ull * 2);
  bf16*  H     = (bf16*)alloc(12582912ull * 2);
  float* Ps    = (float*)alloc(196608ull * 4);
  float* Part  = (float*)alloc(4ull * 3145728ull * 4);   // 4 split-K partials (fc2)

  auto cvt = [&](const float* src, bf16* dst, int n) {
    int n4 = n / 4;
    f32_to_bf16_k<<<(n4 + 255) / 256, 256, 0, stream>>>(src, dst, n4);
  };
  cvt(x, Xb, 3145728);
  cvt(weight, Wb_w, 589824);
  cvt(Wo, Wb_o, 5898240);
  cvt(fc1w, Wb_f1, 2359296);
  cvt(fc2w, Wb_f2, 2359296);
  transpose_wv<<<dim3(12, 12, 10), 256, 0, stream>>>(Wv, WvT);
  pe_kernel<<<384, 256, 0, stream>>>(PEf);

  // Wvo[a] = Wo[a] @ Wv[a]  (A = Wo[a][m,t], B = WvT[a][k,t], batched over z)
  gemm_k<128, EPI_B16><<<dim3(6, 6, 10), 256, 0, stream>>>(
      Wb_o, WvT, nullptr, Wvo, nullptr, 768, 768, 0, 768, 589824, 589824, 589824);

  // T0 = x @ weight^T + PE (split-K x2, 128x64 tiles), fused LN1
  gemm_k<64, EPI_PART><<<dim3(32, 12, 2), 256, 0, stream>>>(
      Xb, Wb_w, Part, nullptr, nullptr, 768, 768, 384, 384, 0, 0, 3145728);
  reduce_ln<2, 0><<<4096, 256, 0, stream>>>(Part, 3145728, PEf, ln1g, ln1b, T, SN);

  for (int a = 0; a < 10; ++a) {
    scan_partial_b<<<dim3(16, 16, 3), 256, 0, stream>>>(SN, Ps);
    scan_final_b<<<dim3(16, 16, 3), 256, 0, stream>>>(SN, Ps, PSb);
    // S1 partials = PS @ Wvo[a]^T  (split-K x2, 128x64 tiles)
    gemm_k<64, EPI_PART><<<dim3(32, 12, 2), 256, 0, stream>>>(
        PSb, Wvo + (size_t)a * 589824, Part, nullptr, nullptr, 768, 768, 384, 384, 0, 0, 3145728);
    reduce_ln<2, 1><<<4096, 256, 0, stream>>>(Part, 3145728, T, ln2g, ln2b, nullptr, SN);
    // fc1: H = gelu(SN2 @ fc1w^T + b) — 8-phase 256x256, grid 16x12
    gemm256<EPI_GELU><<<dim3(16, 12, 1), 512, 0, stream>>>(
        SN, Wb_f1, nullptr, H, fc1b, 768, 3072, 0, 768, 0);
    // fc2 partials: H @ fc2w^T — 8-phase 256x256, split-K x4 (16x3x4)
    gemm256<EPI_PART><<<dim3(16, 3, 4), 512, 0, stream>>>(
        H, Wb_f2, Part, nullptr, nullptr, 3072, 768, 768, 768, 3145728);
    if (a < 9)
      reduce_ln<4, 2><<<4096, 256, 0, stream>>>(Part, 3145728, fc2b, ln1g, ln1b, T, SN);
    else
      reduce_ln<4, 3><<<4096, 256, 0, stream>>>(Part, 3145728, fc2b, nullptr, nullptr, out, nullptr);
  }
  (void)in_sizes; (void)n_in; (void)out_size; (void)ws_size;
}

// Round 6
// 1286.369 us; speedup vs baseline: 1.1121x; 1.0035x over previous
//
#include <hip/hip_runtime.h>
#include <hip/hip_bf16.h>
#include <math.h>

// RTM identities:
//  - softmax over size-1 axis == 1  =>  q,k,Wq,Wk dead; newV == v
//  - token j restarts from s0[:,j]; only cumV couples tokens
//  - prefix-sum linear => fold Wv into Wo: Wvo[a] = Wo[a] @ Wv[a] (once);
//       S1 = PS(LN1(T)) @ Wvo[a]^T + T
// History: R0 (128-tile 2-buf, fc2 splitK x2) = 1249 us, best verified.
// R6 (8ph 256^2 fc1+fc2 splitK x4) = 1291: the +40us is reduce_ln<4>'s extra
// partial traffic; GEMM time was a wash BUT fc1's 8-phase was confounded by
// fc2's. R7 = clean A/B: 8-phase gemm256 on fc1 ONLY; everything else exactly
// R0 (fc2 gemm_k<64> splitK x2, reduce_ln<2>, 2-partial Part).

using bf16   = __bf16;
using bf16x8 = __attribute__((ext_vector_type(8))) __bf16;
using f32x4  = __attribute__((ext_vector_type(4))) float;

#define DEV __device__ __forceinline__

DEV void gload16(const bf16* g, bf16* l) {
  __builtin_amdgcn_global_load_lds(
      (const __attribute__((address_space(1))) unsigned int*)g,
      (__attribute__((address_space(3))) unsigned int*)l, 16, 0, 0);
}

// GELU with A&S 7.1.26 erf (abs err 1.5e-7; << bf16 rounding).
DEV float gelu_f(float x) {
  const float y  = x * 0.70710678118654752f;
  const float ay = fabsf(y);
  const float t  = __builtin_amdgcn_rcpf(__builtin_fmaf(0.3275911f, ay, 1.0f));
  float p = __builtin_fmaf(1.061405429f, t, -1.453152027f);
  p = __builtin_fmaf(p, t, 1.421413741f);
  p = __builtin_fmaf(p, t, -0.284496736f);
  p = __builtin_fmaf(p, t, 0.254829592f);
  p = p * t;
  const float e = __expf(-ay * ay);
  float er = __builtin_fmaf(-p, e, 1.0f);
  er = __builtin_copysignf(er, y);
  return 0.5f * x * (1.0f + er);
}

enum { EPI_PART = 0, EPI_GELU = 1, EPI_B16 = 2 };

#define BARRIER() do { asm volatile("" ::: "memory");                        \
  __builtin_amdgcn_s_barrier(); asm volatile("" ::: "memory"); } while (0)
#define LGKM0_FENCE() do {                                                   \
  asm volatile("s_waitcnt lgkmcnt(0)" ::: "memory");                         \
  __builtin_amdgcn_sched_barrier(0); } while (0)

// 256x256-tile 8-phase GEMM (R5-verified): C = A[M,K] @ B[N,K]^T on K-slice z.
// 512 thr = 8 waves (wr=w>>2 row-half, wc=w&3 col-quarter); per-wave 128x64.
// LDS: As/Bs[2 slots][2 halves][128x64] bf16 = 128 KiB. Swizzle: physical
// 16B chunk p of local row r holds global chunk (p-r)&7; staging pre-swizzles
// the GLOBAL source (LDS dest linear for global_load_lds); reads use
// p=(kc+r)&7 (both-sides-or-neither, rule #21).
// Per K-tile u (slot s=u&1), 4 phases; ONE counted vmcnt(4) per tile:
//   p1: rdA(q0)+rdB | stA(s^1,0,u+1) | bar lgkm0 schedbar prio MFMA q0 bar
//   p2: rdA(q1)     | stA(s^1,1,u+1) | bar lgkm0 schedbar prio MFMA q1 bar
//   p3: rdA(q2)     | stB(s,0,u+2)   | bar lgkm0 schedbar prio MFMA q2 bar
//   p4: rdA(q3)     | stB(s,1,u+2)   | bar lgkm0 schedbar prio MFMA q3
//       vmcnt(4) [tile u+1 fully landed; B(u+2) in flight] bar
template <int EPI>
__global__ __launch_bounds__(512, 2) void gemm256(
    const bf16* __restrict__ A, const bf16* __restrict__ B,
    float* __restrict__ outF, bf16* __restrict__ outB,
    const float* __restrict__ aux, int K, int N,
    int kZ, int klen, size_t oZ)
{
  __shared__ bf16 As[2][2][8192];
  __shared__ bf16 Bs[2][2][8192];
  const int z = blockIdx.z;
  const int kbeg = z * kZ;
  const int NT = klen >> 6;                   // K-tiles of 64
  const int tid = threadIdx.x, lane = tid & 63, w = tid >> 6;
  const int wr = w >> 2, wc = w & 3;
  const int lr = lane & 15, kb = lane >> 4;
  const int bh = wc >> 1, bcol0 = (wc & 1) * 64;
  const int rst = tid >> 3, kcst = ((tid & 7) - (tid >> 3)) & 7;

  // Bijective XCD-chunked tile remap (grids are multiples of 8).
  const int nx = gridDim.x;
  const int nwg = nx * (int)gridDim.y;
  int f = blockIdx.x + nx * blockIdx.y;
  const int xcd = f & 7, idx = f >> 3;
  const int q8 = nwg >> 3, r8 = nwg & 7;
  f = (xcd < r8 ? xcd * (q8 + 1) : r8 * (q8 + 1) + (xcd - r8) * q8) + idx;
  const int m0 = (f % nx) * 256, n0 = (f / nx) * 256;

  const bf16* aG[2] = { A + (size_t)(m0 + rst) * K + kbeg + kcst * 8,
                        A + (size_t)(m0 + 128 + rst) * K + kbeg + kcst * 8 };
  const bf16* bG[2] = { B + (size_t)(n0 + rst) * K + kbeg + kcst * 8,
                        B + (size_t)(n0 + 128 + rst) * K + kbeg + kcst * 8 };

  f32x4 acc[8][4] = {};
  bf16x8 av[4], bv[8];

  auto stA = [&](int slot, int h, int t) {
    bf16* d = &As[slot][h][0] + tid * 8;
    const bf16* g = aG[h] + t * 64;
    gload16(g, d); gload16(g + (size_t)64 * K, d + 4096);
  };
  auto stB = [&](int slot, int h, int t) {
    bf16* d = &Bs[slot][h][0] + tid * 8;
    const bf16* g = bG[h] + t * 64;
    gload16(g, d); gload16(g + (size_t)64 * K, d + 4096);
  };
  auto rdA = [&](int s, int q) {
#pragma unroll
    for (int j = 0; j < 2; ++j)
#pragma unroll
      for (int k = 0; k < 2; ++k) {
        const int row = (2 * q + j) * 16 + lr;
        const int p = ((k * 4 + kb) + (lr & 7)) & 7;
        av[j * 2 + k] = *(const bf16x8*)&As[s][wr][row * 64 + p * 8];
      }
  };
  auto rdB = [&](int s) {
#pragma unroll
    for (int nt = 0; nt < 4; ++nt)
#pragma unroll
      for (int k = 0; k < 2; ++k) {
        const int row = bcol0 + nt * 16 + lr;
        const int p = ((k * 4 + kb) + (lr & 7)) & 7;
        bv[nt * 2 + k] = *(const bf16x8*)&Bs[s][bh][row * 64 + p * 8];
      }
  };
  auto mfmaQ = [&](int q) {
    __builtin_amdgcn_s_setprio(1);
#pragma unroll
    for (int nt = 0; nt < 4; ++nt)
#pragma unroll
      for (int j = 0; j < 2; ++j)
#pragma unroll
        for (int k = 0; k < 2; ++k)
          acc[2 * q + j][nt] = __builtin_amdgcn_mfma_f32_16x16x32_bf16(
              av[j * 2 + k], bv[nt * 2 + k], acc[2 * q + j][nt], 0, 0, 0);
    __builtin_amdgcn_s_setprio(0);
  };

  // Prologue: tile 0 complete + B of tile 1; wait tile 0 only (counted).
  stA(0, 0, 0); stA(0, 1, 0); stB(0, 0, 0); stB(0, 1, 0);
  if (NT > 1) { stB(1, 0, 1); stB(1, 1, 1); }
  if (NT > 1) asm volatile("s_waitcnt vmcnt(4)" ::: "memory");
  else        asm volatile("s_waitcnt vmcnt(0)" ::: "memory");
  BARRIER();

  for (int u = 0; u < NT; ++u) {
    const int s = u & 1;
    const bool g1 = u + 1 < NT, g2 = u + 2 < NT;
    // p1
    rdA(s, 0); rdB(s);
    if (g1) stA(s ^ 1, 0, u + 1);
    BARRIER();
    LGKM0_FENCE();
    mfmaQ(0);
    BARRIER();
    // p2
    rdA(s, 1);
    if (g1) stA(s ^ 1, 1, u + 1);
    BARRIER();
    LGKM0_FENCE();
    mfmaQ(1);
    BARRIER();
    // p3
    rdA(s, 2);
    if (g2) stB(s, 0, u + 2);
    BARRIER();
    LGKM0_FENCE();
    mfmaQ(2);
    BARRIER();
    // p4
    rdA(s, 3);
    if (g2) stB(s, 1, u + 2);
    BARRIER();
    LGKM0_FENCE();
    mfmaQ(3);
    if (g2)      asm volatile("s_waitcnt vmcnt(4)" ::: "memory");
    else if (g1) asm volatile("s_waitcnt vmcnt(0)" ::: "memory");
    BARRIER();
  }

  // C/D layout: col = lane&15, row = (lane>>4)*4 + reg  [verified m89/m91]
  const int row0 = m0 + wr * 128 + (lane >> 4) * 4;
  const int col0 = n0 + wc * 64 + lr;
  float* oF = (EPI == EPI_PART) ? outF + (size_t)z * oZ : nullptr;
#pragma unroll
  for (int mt = 0; mt < 8; ++mt) {
#pragma unroll
    for (int nt = 0; nt < 4; ++nt) {
      const int col = col0 + nt * 16;
      float bias = 0.f;
      if (EPI == EPI_GELU) bias = aux[col];
#pragma unroll
      for (int rg = 0; rg < 4; ++rg) {
        const int row = row0 + mt * 16 + rg;
        float v = acc[mt][nt][rg];
        if (EPI == EPI_PART) {
          oF[(size_t)row * N + col] = v;
        } else {
          outB[(size_t)row * N + col] = (bf16)gelu_f(v + bias);
        }
      }
    }
  }
}

// ---- 128xBN-tile GEMM — exact R0-proven 2-buf loop --------------------------
template <int BN, int EPI>
__global__ __launch_bounds__(256) void gemm_k(
    const bf16* __restrict__ A, const bf16* __restrict__ B,
    float* __restrict__ outF, bf16* __restrict__ outB,
    const float* __restrict__ aux, int K, int N,
    int kZ, int klen, size_t aZ, size_t bZ, size_t oZ)
{
  constexpr int ABUF = 128 * 32;
  constexpr int BBUF = BN * 32;
  __shared__ bf16 Asl[2 * ABUF];
  __shared__ bf16 Bsl[2 * BBUF];
  const int z = blockIdx.z;
  A += (size_t)z * aZ;
  B += (size_t)z * bZ;
  const int kbeg = z * kZ;
  const int tid  = threadIdx.x;
  const int lane = tid & 63, wave = tid >> 6;
  const int m0 = blockIdx.x * 128, n0 = blockIdx.y * BN;

  const int r  = tid >> 2;
  const int kq = ((tid & 3) - (tid >> 3)) & 3;
  const bf16* aG0 = A + (size_t)(m0 + r) * K + kq * 8 + kbeg;
  const bf16* aG1 = aG0 + (size_t)64 * K;
  const bf16* bG0 = B + (size_t)(n0 + r) * K + kq * 8 + kbeg;
  const bf16* bG1 = bG0 + (size_t)64 * K;   // used only for BN==128

  const int wr = (wave & 1) * 64, wc = (wave >> 1) * (BN / 2);
  const int lr = lane & 15, kb = lane >> 4;
  const int swz  = ((kb + (lr >> 1)) & 3) * 8;
  const int aOff = (wr + lr) * 32 + swz;
  const int bOff = (wc + lr) * 32 + swz;

  constexpr int MT = 4, NTT = BN / 32;
  f32x4 acc[MT][NTT] = {};
  const int iters = klen >> 5;

  auto stage = [&](int p, int k0) {
    bf16* aD = &Asl[p * ABUF + tid * 8];
    gload16(aG0 + k0, aD);
    gload16(aG1 + k0, aD + 2048);
    bf16* bD = &Bsl[p * BBUF + tid * 8];
    gload16(bG0 + k0, bD);
    if (BN == 128) gload16(bG1 + k0, bD + 2048);
  };

  stage(0, 0);
  for (int it = 0; it < iters; ++it) {
    __syncthreads();
    if (it + 1 < iters) stage((it + 1) & 1, (it + 1) * 32);
    const int pa = (it & 1) * ABUF, pb = (it & 1) * BBUF;
    bf16x8 af[MT], bfv[NTT];
#pragma unroll
    for (int t = 0; t < MT; ++t) af[t] = *(const bf16x8*)&Asl[pa + aOff + t * 512];
#pragma unroll
    for (int t = 0; t < NTT; ++t) bfv[t] = *(const bf16x8*)&Bsl[pb + bOff + t * 512];
#pragma unroll
    for (int mt = 0; mt < MT; ++mt)
#pragma unroll
      for (int nt = 0; nt < NTT; ++nt)
        acc[mt][nt] = __builtin_amdgcn_mfma_f32_16x16x32_bf16(af[mt], bfv[nt], acc[mt][nt], 0, 0, 0);
  }

  const int row0 = m0 + wr + (lane >> 4) * 4;
  const int col0 = n0 + wc + lr;
  float* oF = (EPI == EPI_PART) ? outF + (size_t)z * oZ : nullptr;
  bf16*  oB = (EPI == EPI_B16)  ? outB + (size_t)z * oZ : outB;
#pragma unroll
  for (int mt = 0; mt < MT; ++mt) {
#pragma unroll
    for (int nt = 0; nt < NTT; ++nt) {
      const int col = col0 + nt * 16;
      float bias = 0.f;
      if (EPI == EPI_GELU) bias = aux[col];
#pragma unroll
      for (int rg = 0; rg < 4; ++rg) {
        const int row = row0 + mt * 16 + rg;
        float v = acc[mt][nt][rg];
        if (EPI == EPI_PART) {
          oF[(size_t)row * N + col] = v;
        } else if (EPI == EPI_GELU) {
          oB[(size_t)row * N + col] = (bf16)gelu_f(v + bias);
        } else {
          oB[(size_t)row * N + col] = (bf16)v;
        }
      }
    }
  }
}

// One 768-row per block; sums NP split-K partials, adds per-MODE term, LN-fuses.
// MODE 0: s = Σp + PE[row&255]; T=s; SN = LN1(s)
// MODE 1: s = Σp + add[row]   ; SN = LN2(s)+s
// MODE 2: s = Σp + bias       ; T=s; SN = LN1(s)
// MODE 3: s = Σp + bias       ; T=s (fp32 out only, last stage)
template <int NP, int MODE>
__global__ __launch_bounds__(256) void reduce_ln(
    const float* __restrict__ P, size_t pZ,
    const float* __restrict__ add, const float* __restrict__ g,
    const float* __restrict__ b, float* __restrict__ Tout,
    bf16* __restrict__ SNout)
{
  const int row = blockIdx.x, t = threadIdx.x;
  float v[3];
#pragma unroll
  for (int c = 0; c < 3; ++c) {
    const int col = t + c * 256;
    float s = P[(size_t)row * 768 + col];
#pragma unroll
    for (int p = 1; p < NP; ++p) s += P[(size_t)p * pZ + (size_t)row * 768 + col];
    if (MODE == 0) s += add[(row & 255) * 768 + col];
    if (MODE == 1) s += add[(size_t)row * 768 + col];
    if (MODE == 2 || MODE == 3) s += add[col];
    v[c] = s;
  }
  if (MODE != 1) {
#pragma unroll
    for (int c = 0; c < 3; ++c) Tout[(size_t)row * 768 + t + c * 256] = v[c];
  }
  if (MODE == 3) return;

  __shared__ float red[8];
  float s = v[0] + v[1] + v[2];
#pragma unroll
  for (int o = 32; o >= 1; o >>= 1) s += __shfl_down(s, o);
  if ((t & 63) == 0) red[t >> 6] = s;
  __syncthreads();
  const float mu = (red[0] + red[1] + red[2] + red[3]) * (1.f / 768.f);
  const float d0 = v[0] - mu, d1 = v[1] - mu, d2 = v[2] - mu;
  float q = d0 * d0 + d1 * d1 + d2 * d2;
#pragma unroll
  for (int o = 32; o >= 1; o >>= 1) q += __shfl_down(q, o);
  if ((t & 63) == 0) red[4 + (t >> 6)] = q;
  __syncthreads();
  const float var = (red[4] + red[5] + red[6] + red[7]) * (1.f / 768.f);
  const float rs = rsqrtf(var + 1e-5f);
  float y0 = d0 * rs * g[t] + b[t];
  float y1 = d1 * rs * g[t + 256] + b[t + 256];
  float y2 = d2 * rs * g[t + 512] + b[t + 512];
  if (MODE == 1) { y0 += v[0]; y1 += v[1]; y2 += v[2]; }
  bf16* o = SNout + (size_t)row * 768;
  o[t] = (bf16)y0; o[t + 256] = (bf16)y1; o[t + 512] = (bf16)y2;
}

// Exclusive prefix over token axis j (256 tokens) of SN[n,j,d], bf16 io.
__global__ __launch_bounds__(256) void scan_partial_b(
    const bf16* __restrict__ SN, float* __restrict__ Ps)
{
  const int n = blockIdx.x, ch = blockIdx.y, d = blockIdx.z * 256 + threadIdx.x;
  const bf16* base = SN + ((size_t)(n * 256 + ch * 16)) * 768 + d;
  float s = 0.f;
#pragma unroll
  for (int j = 0; j < 16; ++j) s += (float)base[(size_t)j * 768];
  Ps[(size_t)(n * 16 + ch) * 768 + d] = s;
}

__global__ __launch_bounds__(256) void scan_final_b(
    const bf16* __restrict__ SN, const float* __restrict__ Ps,
    bf16* __restrict__ PSb)
{
  const int n = blockIdx.x, ch = blockIdx.y, d = blockIdx.z * 256 + threadIdx.x;
  float run = 0.f;
  for (int c = 0; c < ch; ++c) run += Ps[(size_t)(n * 16 + c) * 768 + d];
  const bf16* vb = SN + ((size_t)(n * 256 + ch * 16)) * 768 + d;
  bf16* ob = PSb + ((size_t)(n * 256 + ch * 16)) * 768 + d;
#pragma unroll
  for (int j = 0; j < 16; ++j) {
    ob[(size_t)j * 768] = (bf16)run;
    run += (float)vb[(size_t)j * 768];
  }
}

// WvT[a][n][k] = (bf16)Wv[a][k][n]; 64x64 tiles via LDS (65-float stride).
__global__ __launch_bounds__(256) void transpose_wv(
    const float* __restrict__ Wv, bf16* __restrict__ WvT)
{
  __shared__ float tile[64][65];
  const int a = blockIdx.z, k0 = blockIdx.x * 64, n0 = blockIdx.y * 64;
  const int c = threadIdx.x & 63, r4 = threadIdx.x >> 6;
  const float* src = Wv + (size_t)a * 589824;
  bf16* dst = WvT + (size_t)a * 589824;
#pragma unroll
  for (int i = 0; i < 16; ++i)
    tile[r4 + i * 4][c] = src[(size_t)(k0 + r4 + i * 4) * 768 + n0 + c];
  __syncthreads();
#pragma unroll
  for (int i = 0; i < 16; ++i) {
    const int n = r4 + i * 4;
    dst[(size_t)(n0 + n) * 768 + k0 + c] = (bf16)tile[c][n];
  }
}

__global__ __launch_bounds__(256) void f32_to_bf16_k(
    const float* __restrict__ in, bf16* __restrict__ out, int n4)
{
  const int i = blockIdx.x * 256 + threadIdx.x;
  if (i >= n4) return;
  const float4 v = ((const float4*)in)[i];
  bf16 h[4] = {(bf16)v.x, (bf16)v.y, (bf16)v.z, (bf16)v.w};
  *(uint2*)(out + 4 * (size_t)i) = *(uint2*)h;
}

// pe[j, 2p] = sin(j / 10000^(4p/768)),  pe[j, 2p+1] = cos(...)
__global__ __launch_bounds__(256) void pe_kernel(float* __restrict__ PE)
{
  const int id = blockIdx.x * 256 + threadIdx.x;  // 256*384 total
  const int j = id / 384, p = id % 384;
  const double ang = (double)j * pow(10000.0, -4.0 * (double)p / 768.0);
  PE[(size_t)j * 768 + 2 * p]     = (float)sin(ang);
  PE[(size_t)j * 768 + 2 * p + 1] = (float)cos(ang);
}

extern "C" void kernel_launch(void* const* d_in, const int* in_sizes, int n_in,
                              void* d_out, int out_size, void* d_ws, size_t ws_size,
                              hipStream_t stream)
{
  const float* x      = (const float*)d_in[0];
  const float* weight = (const float*)d_in[1];
  const float* Wv     = (const float*)d_in[4];
  const float* Wo     = (const float*)d_in[5];
  const float* ln1g   = (const float*)d_in[6];
  const float* ln1b   = (const float*)d_in[7];
  const float* ln2g   = (const float*)d_in[8];
  const float* ln2b   = (const float*)d_in[9];
  const float* fc1w   = (const float*)d_in[10];
  const float* fc1b   = (const float*)d_in[11];
  const float* fc2w   = (const float*)d_in[12];
  const float* fc2b   = (const float*)d_in[13];
  float* out = (float*)d_out;

  char* p = (char*)d_ws;
  auto alloc = [&](size_t bytes) { char* r = p; p += (bytes + 255) & ~(size_t)255; return r; };
  bf16*  Wb_w  = (bf16*)alloc(589824ull * 2);
  bf16*  Wb_o  = (bf16*)alloc(5898240ull * 2);
  bf16*  WvT   = (bf16*)alloc(5898240ull * 2);
  bf16*  Wvo   = (bf16*)alloc(5898240ull * 2);
  bf16*  Wb_f1 = (bf16*)alloc(2359296ull * 2);
  bf16*  Wb_f2 = (bf16*)alloc(2359296ull * 2);
  bf16*  Xb    = (bf16*)alloc(3145728ull * 2);
  float* PEf   = (float*)alloc(196608ull * 4);
  float* T     = (float*)alloc(3145728ull * 4);
  bf16*  SN    = (bf16*)alloc(3145728ull * 2);
  bf16*  PSb   = (bf16*)alloc(3145728ull * 2);
  bf16*  H     = (bf16*)alloc(12582912ull * 2);
  float* Ps    = (float*)alloc(196608ull * 4);
  float* Part  = (float*)alloc(2ull * 3145728ull * 4);

  auto cvt = [&](const float* src, bf16* dst, int n) {
    int n4 = n / 4;
    f32_to_bf16_k<<<(n4 + 255) / 256, 256, 0, stream>>>(src, dst, n4);
  };
  cvt(x, Xb, 3145728);
  cvt(weight, Wb_w, 589824);
  cvt(Wo, Wb_o, 5898240);
  cvt(fc1w, Wb_f1, 2359296);
  cvt(fc2w, Wb_f2, 2359296);
  transpose_wv<<<dim3(12, 12, 10), 256, 0, stream>>>(Wv, WvT);
  pe_kernel<<<384, 256, 0, stream>>>(PEf);

  // Wvo[a] = Wo[a] @ Wv[a]  (A = Wo[a][m,t], B = WvT[a][k,t], batched over z)
  gemm_k<128, EPI_B16><<<dim3(6, 6, 10), 256, 0, stream>>>(
      Wb_o, WvT, nullptr, Wvo, nullptr, 768, 768, 0, 768, 589824, 589824, 589824);

  // T0 = x @ weight^T + PE (split-K x2, 128x64 tiles), fused LN1
  gemm_k<64, EPI_PART><<<dim3(32, 12, 2), 256, 0, stream>>>(
      Xb, Wb_w, Part, nullptr, nullptr, 768, 768, 384, 384, 0, 0, 3145728);
  reduce_ln<2, 0><<<4096, 256, 0, stream>>>(Part, 3145728, PEf, ln1g, ln1b, T, SN);

  for (int a = 0; a < 10; ++a) {
    scan_partial_b<<<dim3(16, 16, 3), 256, 0, stream>>>(SN, Ps);
    scan_final_b<<<dim3(16, 16, 3), 256, 0, stream>>>(SN, Ps, PSb);
    // S1 partials = PS @ Wvo[a]^T  (split-K x2, 128x64 tiles)
    gemm_k<64, EPI_PART><<<dim3(32, 12, 2), 256, 0, stream>>>(
        PSb, Wvo + (size_t)a * 589824, Part, nullptr, nullptr, 768, 768, 384, 384, 0, 0, 3145728);
    reduce_ln<2, 1><<<4096, 256, 0, stream>>>(Part, 3145728, T, ln2g, ln2b, nullptr, SN);
    // fc1: H = gelu(SN2 @ fc1w^T + b) — 8-phase 256x256, grid 16x12 (A/B vs R0)
    gemm256<EPI_GELU><<<dim3(16, 12, 1), 512, 0, stream>>>(
        SN, Wb_f1, nullptr, H, fc1b, 768, 3072, 0, 768, 0);
    // fc2 partials: H @ fc2w^T — exact R0: split-K x2, 128x64 tiles
    gemm_k<64, EPI_PART><<<dim3(32, 12, 2), 256, 0, stream>>>(
        H, Wb_f2, Part, nullptr, nullptr, 3072, 768, 1536, 1536, 0, 0, 3145728);
    if (a < 9)
      reduce_ln<2, 2><<<4096, 256, 0, stream>>>(Part, 3145728, fc2b, ln1g, ln1b, T, SN);
    else
      reduce_ln<2, 3><<<4096, 256, 0, stream>>>(Part, 3145728, fc2b, nullptr, nullptr, out, nullptr);
  }
  (void)in_sizes; (void)n_in; (void)out_size; (void)ws_size;
}